// Round 10
// baseline (304.411 us; speedup 1.0000x reference)
//
#include <hip/hip_runtime.h>
#include <hip/hip_bf16.h>

#define NL 2
#define NH 8
#define DKk 32
#define DVv 32
#define DFF 512
#define DD 256
#define BB 2
#define SS 2048
#define MROWS (BB*SS)            // 4096
#define MASK_VALUE (-1e-30f)
#define LN_EPS 1e-14f
#define SOFT_SHIFT 50.0f

typedef __hip_bfloat16 bf16;
typedef unsigned short us;
typedef short bf16x8 __attribute__((ext_vector_type(8)));   // 8 bf16 = 4 VGPRs
typedef float f32x4  __attribute__((ext_vector_type(4)));
typedef unsigned short us4 __attribute__((ext_vector_type(4)));

// ---- workspace layout (floats) ----
#define O_XF   256
#define O_QB   (O_XF+1048576)
#define O_KH   (O_QB+1048576)
#define O_KL   (O_KH+524288)
#define O_VT   (O_KL+524288)
#define O_XH   (O_VT+524288)       // x pre-split hi (1048576 us)
#define O_XL   (O_XH+524288)       // x pre-split lo
#define O_OP   (O_XL+524288)       // 4194304: key-split x4 partial O (fh aliases)
#define O_ML   (O_OP+4194304)      // 131072: key-split l (m is constant)
#define O_MASK (O_ML+131072)
#define O_WQ   (O_MASK+4096)
#define O_WK   (O_WQ+131072)
#define O_WV   (O_WK+131072)
#define O_WO   (O_WV+131072)
#define O_W1   (O_WO+131072)
#define O_B1   (O_W1+262144)
#define O_W2   (O_B1+1024)
#define O_B2   (O_W2+262144)
#define O_GM   (O_B2+512)
#define O_BT   (O_GM+4)
#define O_PREP (O_BT+4)
// total elements mega_conv must cover (x..beta):
#define CONV_TOTAL (1048576+4096+131072+131072+131072+131072+262144+1024+262144+512+4+4)
#define CONV_BLOCKS ((CONV_TOTAL+255)/256)   // covers gamma/beta (R7 bug: 8214)
// prep region offsets in ushorts (relative to (us*)(ws+O_PREP))
#define PQH 0u
#define PQL 393216u
#define POH 786432u
#define POL 917504u
#define P1H 1048576u
#define P1L 1310720u
#define P2H 1572864u
#define P2L 1835008u

__device__ __forceinline__ float us2f(us u){
  unsigned int v = ((unsigned int)u) << 16; float f;
  __builtin_memcpy(&f, &v, 4); return f;
}
__device__ __forceinline__ us f2bf_rne(float f){
  unsigned int b = __float_as_uint(f);
  b += 0x7FFFu + ((b>>16)&1u);
  return (us)(b>>16);
}

// x pre-split frag-major index for element (row, col), K=256 tiling.
__device__ __forceinline__ size_t xhl_idx(int row, int col){
  int rt = row>>6, rg = (row>>4)&3, L15 = row&15;
  int kc = col>>5, Q = (col>>3)&3, j = col&7;
  return ((size_t)(rt*8+kc))*2048 + rg*512 + Q*128 + L15*8 + j;
}

// Detect whether inputs are bf16 (flag=0) or fp32 (flag=1).
__global__ void detect_kernel(const us* __restrict__ x, int n, int* __restrict__ flagp){
  __shared__ int bad;
  if(threadIdx.x==0) bad = 0;
  __syncthreads();
  int lim = n < 4096 ? n : 4096;
  int mybad = 0;
  for(int i=threadIdx.x; i<lim; i+=256){
    float f = us2f(x[i]);
    if(!(fabsf(f) < 1e3f)) mybad = 1;
  }
  if(mybad) atomicOr(&bad, 1);
  __syncthreads();
  if(threadIdx.x==0) *flagp = bad ? 1 : 0;
}

__device__ __forceinline__ float conv1(const void* src, int i, int flag){
  if(flag) return ((const float*)src)[i];
  return us2f(((const us*)src)[i]);
}

// All 12 input conversions in one dispatch; x also emitted pre-split (xhl).
__global__ void mega_conv(const void* s0, const void* s1, const void* s2, const void* s3,
                          const void* s4, const void* s5, const void* s6, const void* s7,
                          const void* s8, const void* s9, const void* s10, const void* s11,
                          float* __restrict__ ws, const int* __restrict__ flagp)
{
  int g = blockIdx.x*256 + threadIdx.x;
  int flag = *flagp;
  if(g < 1048576){
    float v = conv1(s0, g, flag);
    ws[O_XF+g] = v;
    us hb = f2bf_rne(v);
    us lb = f2bf_rne(v - us2f(hb));
    size_t xi = xhl_idx(g>>8, g&255);
    ((us*)(ws+O_XH))[xi] = hb;
    ((us*)(ws+O_XL))[xi] = lb;
    return;
  }
  g -= 1048576;
  if(g < 4096){ ws[O_MASK+g] = conv1(s1, g, flag); return; }
  g -= 4096;
  if(g < 131072){ ws[O_WQ+g] = conv1(s2, g, flag); return; }
  g -= 131072;
  if(g < 131072){ ws[O_WK+g] = conv1(s3, g, flag); return; }
  g -= 131072;
  if(g < 131072){ ws[O_WV+g] = conv1(s4, g, flag); return; }
  g -= 131072;
  if(g < 131072){ ws[O_WO+g] = conv1(s5, g, flag); return; }
  g -= 131072;
  if(g < 262144){ ws[O_W1+g] = conv1(s6, g, flag); return; }
  g -= 262144;
  if(g < 1024){ ws[O_B1+g] = conv1(s7, g, flag); return; }
  g -= 1024;
  if(g < 262144){ ws[O_W2+g] = conv1(s8, g, flag); return; }
  g -= 262144;
  if(g < 512){ ws[O_B2+g] = conv1(s9, g, flag); return; }
  g -= 512;
  if(g < 4){ ws[O_GM+g] = conv1(s10, g, flag); return; }
  g -= 4;
  if(g < 4){ ws[O_BT+g] = conv1(s11, g, flag); return; }
}

// Build fragment-major hi/lo bf16 B-operands from fp32 weights.
__device__ __forceinline__ void prep_b(const float* W0, const float* W1, const float* W2,
                                       us* Bh, us* Bl, int Kd, int Nd, int qkv, int g)
{
  int total = (Kd/32)*(Nd/16)*64;
  if(g >= total) return;
  int lane = g & 63, fi = g >> 6;
  int ncN = Nd/16;
  int nc = fi % ncN, kc = fi / ncN;
  int Q = lane>>4, L15 = lane&15;
  int n = nc*16 + L15;
  const float* src;
  int stride;
  if(qkv){
    int sec = n>>8, h = (n>>5)&7, kq = n&31;
    const float* Wp = (sec==0)?W0:((sec==1)?W1:W2);
    src = Wp + (size_t)h*256*32 + kq;
    stride = 32;
  } else {
    src = W0 + n;
    stride = Nd;
  }
  #pragma unroll
  for(int j=0;j<8;j++){
    int k = kc*32 + Q*8 + j;
    float v = src[(size_t)k*stride];
    us hb = f2bf_rne(v);
    Bh[(size_t)g*8 + j] = hb;
    Bl[(size_t)g*8 + j] = f2bf_rne(v - us2f(hb));
  }
}

// All 8 weight-prep jobs in one dispatch (block-range routing, 512 blocks).
__global__ void mega_prep(float* __restrict__ ws)
{
  int gb = blockIdx.x;
  int layer = gb >> 8, lb = gb & 255;
  us* prep = (us*)(ws + O_PREP);
  const float* Wq = ws + O_WQ + layer*65536;
  const float* Wk = ws + O_WK + layer*65536;
  const float* Wv = ws + O_WV + layer*65536;
  const float* Wo = ws + O_WO + layer*65536;
  const float* W1 = ws + O_W1 + layer*131072;
  const float* W2 = ws + O_W2 + layer*131072;
  if(lb < 96){
    int g = lb*256 + threadIdx.x;
    prep_b(Wq, Wk, Wv, prep+PQH+(size_t)layer*196608, prep+PQL+(size_t)layer*196608, 256, 768, 1, g);
  } else if(lb < 128){
    int g = (lb-96)*256 + threadIdx.x;
    prep_b(Wo, nullptr, nullptr, prep+POH+(size_t)layer*65536, prep+POL+(size_t)layer*65536, 256, 256, 0, g);
  } else if(lb < 192){
    int g = (lb-128)*256 + threadIdx.x;
    prep_b(W1, nullptr, nullptr, prep+P1H+(size_t)layer*131072, prep+P1L+(size_t)layer*131072, 256, 512, 0, g);
  } else {
    int g = (lb-192)*256 + threadIdx.x;
    prep_b(W2, nullptr, nullptr, prep+P2H+(size_t)layer*131072, prep+P2L+(size_t)layer*131072, 512, 256, 0, g);
  }
}

// Split-bf16 MFMA GEMM. Tile 64x64, 4 waves, 3 MFMAs/frag/K32.
// ASRC 0: A fp32, convert in staging. ASRC 1: A pre-split (Axh/Axl frag-major).
// ASRC 2: A = merged attention out (sum of 4 key-split partials / sum l).
// MODE 0: QKV -> q fp32; Khi/Klo frag-major; V^T frag-major.
// MODE 1: res+acc. MODE 2: relu(acc+bias). MODE 3: res+acc+bias.
template<int MODE, int ASRC>
__launch_bounds__(256)
__global__ void gemm_mfma(const float* __restrict__ A,
                          const us* __restrict__ Axh, const us* __restrict__ Axl,
                          const float* __restrict__ OpartA, const float* __restrict__ MLA,
                          const us* __restrict__ Bh, const us* __restrict__ Bl,
                          const float* __restrict__ bias, const float* __restrict__ res,
                          float* __restrict__ O,
                          float* __restrict__ qb, us* __restrict__ KH,
                          us* __restrict__ KL, us* __restrict__ VT,
                          int Ncols, int Kdim)
{
  __shared__ __align__(16) us Ah[2048], Al[2048];
  __shared__ __align__(16) us Bhs[2048], Bls[2048];
  const int t = threadIdx.x;
  const int w = t>>6, lane = t&63;
  const int Q = lane>>4, L15 = lane&15;
  const int row0 = blockIdx.x*64;
  const int nc0 = blockIdx.y*4;
  const int col0 = blockIdx.y*64;

  f32x4 acc[2][2];
  #pragma unroll
  for(int i=0;i<2;i++)
    #pragma unroll
    for(int j=0;j<2;j++) acc[i][j] = (f32x4){0.f,0.f,0.f,0.f};

  const int r1 = t>>3;
  const int kl = (t&7)*4;
  const int Qc = kl>>3, j0 = kl&7;
  const int nKc = Kdim>>5;
  const int ncW = Ncols>>4;

  for(int kc=0; kc<nKc; kc++){
    if(ASRC==1){
      size_t abase = ((size_t)(blockIdx.x*nKc + kc))*2048;
      *(bf16x8*)&Ah[t*8] = *(const bf16x8*)&Axh[abase + (size_t)t*8];
      *(bf16x8*)&Al[t*8] = *(const bf16x8*)&Axl[abase + (size_t)t*8];
    } else {
      #pragma unroll
      for(int half=0; half<2; half++){
        int r = r1 + half*32;
        int rg = r>>4, L = r&15;
        float4 v;
        if(ASRC==2){
          int row = row0 + r;
          int b_ = row>>11, s_ = row&2047;
          size_t i0 = (size_t)(b_*8 + kc)*2048 + s_;     // h == kc (Kdim=256)
          float l = MLA[i0] + MLA[i0+32768] + MLA[i0+65536] + MLA[i0+98304];
          float inv = 1.f/l;
          float4 o0 = *(const float4*)&OpartA[i0*32 + kl];
          float4 o1 = *(const float4*)&OpartA[(i0+32768)*32 + kl];
          float4 o2 = *(const float4*)&OpartA[(i0+65536)*32 + kl];
          float4 o3 = *(const float4*)&OpartA[(i0+98304)*32 + kl];
          v.x=(o0.x+o1.x+o2.x+o3.x)*inv; v.y=(o0.y+o1.y+o2.y+o3.y)*inv;
          v.z=(o0.z+o1.z+o2.z+o3.z)*inv; v.w=(o0.w+o1.w+o2.w+o3.w)*inv;
        } else {
          v = *(const float4*)&A[(size_t)(row0+r)*Kdim + kc*32 + kl];
        }
        float f[4] = {v.x, v.y, v.z, v.w};
        us4 h4, l4;
        #pragma unroll
        for(int j=0;j<4;j++){
          us hb = f2bf_rne(f[j]);
          h4[j] = hb; l4[j] = f2bf_rne(f[j] - us2f(hb));
        }
        int off = (rg*4+Qc)*128 + L*8 + j0;
        *(us4*)&Ah[off] = h4;
        *(us4*)&Al[off] = l4;
      }
    }
    {
      size_t gidx = ((size_t)(kc*ncW + nc0 + (t>>6))*64 + (t&63))*8;
      *(bf16x8*)&Bhs[t*8] = *(const bf16x8*)&Bh[gidx];
      *(bf16x8*)&Bls[t*8] = *(const bf16x8*)&Bl[gidx];
    }
    __syncthreads();

    bf16x8 aAh[2], aAl[2], bBh[2], bBl[2];
    #pragma unroll
    for(int rg2=0;rg2<2;rg2++){
      int rg = (w&1)*2 + rg2;
      aAh[rg2] = *(const bf16x8*)&Ah[rg*512 + lane*8];
      aAl[rg2] = *(const bf16x8*)&Al[rg*512 + lane*8];
    }
    #pragma unroll
    for(int cg2=0;cg2<2;cg2++){
      int nc = (w>>1)*2 + cg2;
      bBh[cg2] = *(const bf16x8*)&Bhs[nc*512 + lane*8];
      bBl[cg2] = *(const bf16x8*)&Bls[nc*512 + lane*8];
    }
    #pragma unroll
    for(int rg2=0;rg2<2;rg2++)
      #pragma unroll
      for(int cg2=0;cg2<2;cg2++){
        acc[rg2][cg2] = __builtin_amdgcn_mfma_f32_16x16x32_bf16(aAl[rg2], bBh[cg2], acc[rg2][cg2], 0,0,0);
        acc[rg2][cg2] = __builtin_amdgcn_mfma_f32_16x16x32_bf16(aAh[rg2], bBl[cg2], acc[rg2][cg2], 0,0,0);
        acc[rg2][cg2] = __builtin_amdgcn_mfma_f32_16x16x32_bf16(aAh[rg2], bBh[cg2], acc[rg2][cg2], 0,0,0);
      }
    __syncthreads();
  }

  #pragma unroll
  for(int rg2=0;rg2<2;rg2++)
    #pragma unroll
    for(int cg2=0;cg2<2;cg2++)
      #pragma unroll
      for(int r=0;r<4;r++){
        int row = row0 + (w&1)*32 + rg2*16 + Q*4 + r;
        int c   = col0 + (w>>1)*32 + cg2*16 + L15;
        float va = acc[rg2][cg2][r];
        if(MODE==0){
          int b_ = row>>11, s_ = row&2047;
          int sec = c>>8, h = (c>>5)&7, kq = c&31;
          int bh = b_*NH + h;
          if(sec==0){
            qb[((size_t)bh*SS + s_)*DKk + kq] = va;
          } else if(sec==1){
            us hb = f2bf_rne(va);
            us lb = f2bf_rne(va - us2f(hb));
            size_t idx = ((size_t)(bh*128 + (s_>>4))*64 + (kq>>3)*16 + (s_&15))*8 + (kq&7);
            KH[idx] = hb; KL[idx] = lb;
          } else {
            size_t idx = ((size_t)((bh*64 + (s_>>5))*2 + (kq>>4))*64 + ((s_&31)>>3)*16 + (kq&15))*8 + (s_&7);
            VT[idx] = f2bf_rne(va);
          }
        } else if(MODE==1){
          O[(size_t)row*Ncols + c] = res[(size_t)row*Ncols + c] + va;
        } else if(MODE==2){
          float v = va + bias[c];
          O[(size_t)row*Ncols + c] = v>0.f ? v : 0.f;
        } else {
          O[(size_t)row*Ncols + c] = res[(size_t)row*Ncols + c] + va + bias[c];
        }
      }
}

// MFMA flash attention v5: fixed-shift softmax + key-split x4.
// Grid 2048: bh = bx>>7, qt = (bx>>2)&31, ks = bx&3.
// Block = 4 waves = 64 q-rows of one bh over keys [ks*512, +512).
__launch_bounds__(256)
__global__ void attn_kernel(const float* __restrict__ qb,
                            const us* __restrict__ KH, const us* __restrict__ KL,
                            const us* __restrict__ VT,
                            const float* __restrict__ mask,
                            float* __restrict__ Opart, float* __restrict__ ML)
{
  __shared__ __align__(16) us Khs[4096], Kls[4096], Vts[4096];
  __shared__ __align__(16) float Msl[128];
  const int t = threadIdx.x;
  const int bh = blockIdx.x >> 7;
  const int qt = (blockIdx.x >> 2) & 31;
  const int ks = blockIdx.x & 3;
  const int b_ = bh >> 3;
  const int wv = t >> 6;
  const int lane = t & 63;
  const int Q = lane >> 4, L15 = lane & 15;
  const int q0 = qt*64 + wv*16;

  bf16x8 qh_v, ql_v;
  {
    const float* qp = &qb[((size_t)bh*SS + q0 + L15)*DKk + Q*8];
    union { us u[8]; bf16x8 v; } uh, ul;
    #pragma unroll
    for(int j=0;j<8;j++){
      float f = qp[j];
      us hb = f2bf_rne(f);
      uh.u[j] = hb; ul.u[j] = f2bf_rne(f - us2f(hb));
    }
    qh_v = uh.v; ql_v = ul.v;
  }

  const us* KHbh = KH + (size_t)bh*65536;
  const us* KLbh = KL + (size_t)bh*65536;
  const us* VTbh = VT + (size_t)bh*65536;

  f32x4 Oa0a = {0.f,0.f,0.f,0.f}, Oa0b = {0.f,0.f,0.f,0.f};
  f32x4 Oa1a = {0.f,0.f,0.f,0.f}, Oa1b = {0.f,0.f,0.f,0.f};
  float lacc = 0.f;

  const int kend = ks*512 + 512;
  for(int t0 = ks*512; t0 < kend; t0 += 128){
    {
      size_t kbase = (size_t)(t0>>4)*512;
      size_t vbase = (size_t)(t0>>5)*1024;
      #pragma unroll
      for(int ii=0; ii<2; ii++){
        int s = t + ii*256;
        *(bf16x8*)&Khs[s*8] = *(const bf16x8*)&KHbh[kbase + (size_t)s*8];
        *(bf16x8*)&Kls[s*8] = *(const bf16x8*)&KLbh[kbase + (size_t)s*8];
        *(bf16x8*)&Vts[s*8] = *(const bf16x8*)&VTbh[vbase + (size_t)s*8];
      }
      if(t < 128) Msl[t] = mask[b_*SS + t0 + t];
    }
    __syncthreads();

    // QK^T -> S^T (3 MFMAs per 16-key tile, 8 tiles)
    f32x4 St[8];
    const f32x4 zz = {0.f,0.f,0.f,0.f};
    #pragma unroll
    for(int kt=0;kt<8;kt++){
      bf16x8 aKh = *(const bf16x8*)&Khs[kt*512 + lane*8];
      bf16x8 aKl = *(const bf16x8*)&Kls[kt*512 + lane*8];
      f32x4 a = __builtin_amdgcn_mfma_f32_16x16x32_bf16(aKl, qh_v, zz, 0,0,0);
      a = __builtin_amdgcn_mfma_f32_16x16x32_bf16(aKh, ql_v, a, 0,0,0);
      a = __builtin_amdgcn_mfma_f32_16x16x32_bf16(aKh, qh_v, a, 0,0,0);
      St[kt] = a;
    }

    // fixed-shift softmax: p = exp(mv*S - 50); no max, no rescale
    float lsum = 0.f;
    #pragma unroll
    for(int kt=0;kt<8;kt++){
      float4 mv = *(const float4*)&Msl[kt*16 + Q*4];
      float mvr[4] = {mv.x, mv.y, mv.z, mv.w};
      #pragma unroll
      for(int r=0;r<4;r++){
        float p = __expf(fmaf(mvr[r], St[kt][r], -SOFT_SHIFT));
        St[kt][r] = p;
        lsum += p;
      }
    }
    lacc += lsum;

    // pack P -> bf16 pairs
    int pk[8][2];
    #pragma unroll
    for(int kt=0;kt<8;kt++){
      int b0 = __float_as_int(St[kt][0]) + 0x8000;
      int b1 = __float_as_int(St[kt][1]) + 0x8000;
      int b2 = __float_as_int(St[kt][2]) + 0x8000;
      int b3 = __float_as_int(St[kt][3]) + 0x8000;
      pk[kt][0] = (b1 & 0xFFFF0000) | ((unsigned)b0 >> 16);
      pk[kt][1] = (b3 & 0xFFFF0000) | ((unsigned)b2 >> 16);
    }

    // PV: O^T += V^T · P^T (chunks 0,1 -> a; 2,3 -> b)
    #pragma unroll
    for(int c=0;c<4;c++){
      union { int i[4]; bf16x8 v; } bu;
      #pragma unroll
      for(int d=0;d<4;d++){
        int srcl = (((Q&1)*2 + (d>>1))<<4) | L15;
        int vlo = __shfl(pk[2*c  ][d&1], srcl, 64);
        int vhi = __shfl(pk[2*c+1][d&1], srcl, 64);
        bu.i[d] = (Q & 2) ? vhi : vlo;
      }
      bf16x8 aV0 = *(const bf16x8*)&Vts[(c*2+0)*512 + lane*8];
      bf16x8 aV1 = *(const bf16x8*)&Vts[(c*2+1)*512 + lane*8];
      if(c < 2){
        Oa0a = __builtin_amdgcn_mfma_f32_16x16x32_bf16(aV0, bu.v, Oa0a, 0,0,0);
        Oa1a = __builtin_amdgcn_mfma_f32_16x16x32_bf16(aV1, bu.v, Oa1a, 0,0,0);
      } else {
        Oa0b = __builtin_amdgcn_mfma_f32_16x16x32_bf16(aV0, bu.v, Oa0b, 0,0,0);
        Oa1b = __builtin_amdgcn_mfma_f32_16x16x32_bf16(aV1, bu.v, Oa1b, 0,0,0);
      }
    }
    __syncthreads();
  }

  f32x4 Oa0 = Oa0a + Oa0b;
  f32x4 Oa1 = Oa1a + Oa1b;
  lacc += __shfl_xor(lacc, 16);
  lacc += __shfl_xor(lacc, 32);

  float* opp = &Opart[((size_t)(ks*16+bh)*SS + q0 + L15)*32];
  #pragma unroll
  for(int r=0;r<4;r++){
    opp[Q*4+r]    = Oa0[r];
    opp[16+Q*4+r] = Oa1[r];
  }
  if(Q==0){
    ML[(size_t)(ks*16+bh)*SS + q0 + L15] = lacc;
  }
}

// LayerNorm over D=256, one row per block, in-place; shfl-based reduction.
// Also emits pre-split xhl and (optionally) the final output.
__launch_bounds__(256)
__global__ void ln_kernel(float* __restrict__ xf, const float* __restrict__ gamma,
                          const float* __restrict__ beta, int gi,
                          us* __restrict__ xh, us* __restrict__ xl,
                          void* __restrict__ out, int write_out,
                          const int* __restrict__ flagp)
{
  __shared__ float s1[4], s2[4];
  const int r = blockIdx.x;
  const int t = threadIdx.x;
  float v = xf[(size_t)r*DD + t];
  float sum = v, sumsq = v*v;
  #pragma unroll
  for(int off=1; off<64; off<<=1){
    sum   += __shfl_xor(sum, off);
    sumsq += __shfl_xor(sumsq, off);
  }
  if((t&63)==0){ s1[t>>6]=sum; s2[t>>6]=sumsq; }
  __syncthreads();
  float tot  = s1[0]+s1[1]+s1[2]+s1[3];
  float tot2 = s2[0]+s2[1]+s2[2]+s2[3];
  float mean = tot*(1.f/DD);
  float var  = tot2*(1.f/DD) - mean*mean;
  float g = gamma[gi], bb = beta[gi];
  float val = (v-mean)*rsqrtf(var+LN_EPS)*g + bb;
  xf[(size_t)r*DD + t] = val;
  us hb = f2bf_rne(val);
  us lb = f2bf_rne(val - us2f(hb));
  size_t xi = xhl_idx(r, t);
  xh[xi] = hb; xl[xi] = lb;
  if(write_out){
    if(*flagp) ((float*)out)[(size_t)r*DD + t] = val;
    else       ((bf16*)out)[(size_t)r*DD + t] = __float2bfloat16(val);
  }
}

extern "C" void kernel_launch(void* const* d_in, const int* in_sizes, int n_in,
                              void* d_out, int out_size, void* d_ws, size_t ws_size,
                              hipStream_t stream)
{
  float* ws = (float*)d_ws;
  int* flagp = (int*)d_ws;

  float* xf  = ws + O_XF;
  float* qb  = ws + O_QB;
  us* KH = (us*)(ws + O_KH);
  us* KL = (us*)(ws + O_KL);
  us* VT = (us*)(ws + O_VT);
  us* XH = (us*)(ws + O_XH);
  us* XL = (us*)(ws + O_XL);
  float* Opart = ws + O_OP;
  float* ML  = ws + O_ML;
  float* fh  = Opart;                   // FFN hidden aliases Opart (dead after Wo-GEMM)
  float* maskf = ws + O_MASK;
  float* b1f = ws + O_B1;
  float* b2f_ = ws + O_B2;
  float* gmf = ws + O_GM;
  float* btf = ws + O_BT;
  us* prep = (us*)(ws + O_PREP);

  detect_kernel<<<1,256,0,stream>>>((const us*)d_in[0], in_sizes[0], flagp);
  mega_conv<<<CONV_BLOCKS,256,0,stream>>>(d_in[0], d_in[1], d_in[2], d_in[3], d_in[4], d_in[5],
                                          d_in[6], d_in[7], d_in[8], d_in[9], d_in[10], d_in[11],
                                          ws, flagp);
  mega_prep<<<512,256,0,stream>>>(ws);

  for(int i=0;i<NL;i++){
    const float* b1i = b1f + (size_t)i*DFF;
    const float* b2i = b2f_ + (size_t)i*DD;

    dim3 g0(64, 12);
    gemm_mfma<0,1><<<g0,256,0,stream>>>(nullptr, XH, XL, nullptr, nullptr,
                                        prep+PQH+(size_t)i*196608, prep+PQL+(size_t)i*196608,
                                        nullptr, nullptr, nullptr, qb, KH, KL, VT, 768, 256);
    attn_kernel<<<2048,256,0,stream>>>(qb, KH, KL, VT, maskf, Opart, ML);
    dim3 g1(64, 4);
    gemm_mfma<1,2><<<g1,256,0,stream>>>(nullptr, nullptr, nullptr, Opart, ML,
                                        prep+POH+(size_t)i*65536, prep+POL+(size_t)i*65536,
                                        nullptr, xf, xf, nullptr, nullptr, nullptr, nullptr, 256, 256);
    ln_kernel<<<MROWS,256,0,stream>>>(xf, gmf, btf, 2*i, XH, XL, d_out, 0, flagp);
    dim3 g2(64, 8);
    gemm_mfma<2,1><<<g2,256,0,stream>>>(nullptr, XH, XL, nullptr, nullptr,
                                        prep+P1H+(size_t)i*131072, prep+P1L+(size_t)i*131072,
                                        b1i, nullptr, fh, nullptr, nullptr, nullptr, nullptr, 512, 256);
    dim3 g3(64, 4);
    gemm_mfma<3,0><<<g3,256,0,stream>>>(fh, nullptr, nullptr, nullptr, nullptr,
                                        prep+P2H+(size_t)i*131072, prep+P2L+(size_t)i*131072,
                                        b2i, xf, xf, nullptr, nullptr, nullptr, nullptr, 256, 512);
    ln_kernel<<<MROWS,256,0,stream>>>(xf, gmf, btf, 2*i+1, XH, XL, d_out, (i==NL-1)?1:0, flagp);
  }
}

// Round 11
// 284.091 us; speedup vs baseline: 1.0715x; 1.0715x over previous
//
#include <hip/hip_runtime.h>
#include <hip/hip_bf16.h>

#define NL 2
#define NH 8
#define DKk 32
#define DVv 32
#define DFF 512
#define DD 256
#define BB 2
#define SS 2048
#define MROWS (BB*SS)            // 4096
#define MASK_VALUE (-1e-30f)
#define LN_EPS 1e-14f
#define SOFT_SHIFT 50.0f

typedef __hip_bfloat16 bf16;
typedef unsigned short us;
typedef short bf16x8 __attribute__((ext_vector_type(8)));   // 8 bf16 = 4 VGPRs
typedef float f32x4  __attribute__((ext_vector_type(4)));
typedef unsigned short us4 __attribute__((ext_vector_type(4)));

// ---- workspace layout (floats) ----
#define O_XF   256
#define O_QB   (O_XF+1048576)
#define O_KH   (O_QB+1048576)
#define O_KL   (O_KH+524288)
#define O_VT   (O_KL+524288)
#define O_XH   (O_VT+524288)       // x pre-split hi (1048576 us)
#define O_XL   (O_XH+524288)       // x pre-split lo
#define O_OP   (O_XL+524288)       // 2097152: key-split x2 partial O (fh aliases)
#define O_ML   (O_OP+2097152)      // 65536: key-split l (m is constant)
#define O_MASK (O_ML+65536)
#define O_WQ   (O_MASK+4096)
#define O_WK   (O_WQ+131072)
#define O_WV   (O_WK+131072)
#define O_WO   (O_WV+131072)
#define O_W1   (O_WO+131072)
#define O_B1   (O_W1+262144)
#define O_W2   (O_B1+1024)
#define O_B2   (O_W2+262144)
#define O_GM   (O_B2+512)
#define O_BT   (O_GM+4)
#define O_PREP (O_BT+4)
// total elements mega_conv must cover (x..beta):
#define CONV_TOTAL (1048576+4096+131072+131072+131072+131072+262144+1024+262144+512+4+4)
#define CONV_BLOCKS ((CONV_TOTAL+255)/256)   // covers gamma/beta (R7 bug: 8214)
// prep region offsets in ushorts (relative to (us*)(ws+O_PREP))
#define PQH 0u
#define PQL 393216u
#define POH 786432u
#define POL 917504u
#define P1H 1048576u
#define P1L 1310720u
#define P2H 1572864u
#define P2L 1835008u

__device__ __forceinline__ float us2f(us u){
  unsigned int v = ((unsigned int)u) << 16; float f;
  __builtin_memcpy(&f, &v, 4); return f;
}
__device__ __forceinline__ us f2bf_rne(float f){
  unsigned int b = __float_as_uint(f);
  b += 0x7FFFu + ((b>>16)&1u);
  return (us)(b>>16);
}

// Async global->LDS 16B copy. LDS dest semantics: wave-uniform base + lane*16;
// all call sites use lane-linear 16B layouts so per-lane ptr == HW dest.
__device__ __forceinline__ void gl_lds16(const us* g, us* l){
  __builtin_amdgcn_global_load_lds(
    (const __attribute__((address_space(1))) unsigned int*)g,
    (__attribute__((address_space(3))) unsigned int*)l, 16, 0, 0);
}

// x pre-split frag-major index for element (row, col), K=256 tiling.
__device__ __forceinline__ size_t xhl_idx(int row, int col){
  int rt = row>>6, rg = (row>>4)&3, L15 = row&15;
  int kc = col>>5, Q = (col>>3)&3, j = col&7;
  return ((size_t)(rt*8+kc))*2048 + rg*512 + Q*128 + L15*8 + j;
}

// Detect whether inputs are bf16 (flag=0) or fp32 (flag=1).
__global__ void detect_kernel(const us* __restrict__ x, int n, int* __restrict__ flagp){
  __shared__ int bad;
  if(threadIdx.x==0) bad = 0;
  __syncthreads();
  int lim = n < 4096 ? n : 4096;
  int mybad = 0;
  for(int i=threadIdx.x; i<lim; i+=256){
    float f = us2f(x[i]);
    if(!(fabsf(f) < 1e3f)) mybad = 1;
  }
  if(mybad) atomicOr(&bad, 1);
  __syncthreads();
  if(threadIdx.x==0) *flagp = bad ? 1 : 0;
}

__device__ __forceinline__ float conv1(const void* src, int i, int flag){
  if(flag) return ((const float*)src)[i];
  return us2f(((const us*)src)[i]);
}

// All 12 input conversions in one dispatch; x also emitted pre-split (xhl).
__global__ void mega_conv(const void* s0, const void* s1, const void* s2, const void* s3,
                          const void* s4, const void* s5, const void* s6, const void* s7,
                          const void* s8, const void* s9, const void* s10, const void* s11,
                          float* __restrict__ ws, const int* __restrict__ flagp)
{
  int g = blockIdx.x*256 + threadIdx.x;
  int flag = *flagp;
  if(g < 1048576){
    float v = conv1(s0, g, flag);
    ws[O_XF+g] = v;
    us hb = f2bf_rne(v);
    us lb = f2bf_rne(v - us2f(hb));
    size_t xi = xhl_idx(g>>8, g&255);
    ((us*)(ws+O_XH))[xi] = hb;
    ((us*)(ws+O_XL))[xi] = lb;
    return;
  }
  g -= 1048576;
  if(g < 4096){ ws[O_MASK+g] = conv1(s1, g, flag); return; }
  g -= 4096;
  if(g < 131072){ ws[O_WQ+g] = conv1(s2, g, flag); return; }
  g -= 131072;
  if(g < 131072){ ws[O_WK+g] = conv1(s3, g, flag); return; }
  g -= 131072;
  if(g < 131072){ ws[O_WV+g] = conv1(s4, g, flag); return; }
  g -= 131072;
  if(g < 131072){ ws[O_WO+g] = conv1(s5, g, flag); return; }
  g -= 131072;
  if(g < 262144){ ws[O_W1+g] = conv1(s6, g, flag); return; }
  g -= 262144;
  if(g < 1024){ ws[O_B1+g] = conv1(s7, g, flag); return; }
  g -= 1024;
  if(g < 262144){ ws[O_W2+g] = conv1(s8, g, flag); return; }
  g -= 262144;
  if(g < 512){ ws[O_B2+g] = conv1(s9, g, flag); return; }
  g -= 512;
  if(g < 4){ ws[O_GM+g] = conv1(s10, g, flag); return; }
  g -= 4;
  if(g < 4){ ws[O_BT+g] = conv1(s11, g, flag); return; }
}

// Build fragment-major hi/lo bf16 B-operands from fp32 weights.
__device__ __forceinline__ void prep_b(const float* W0, const float* W1, const float* W2,
                                       us* Bh, us* Bl, int Kd, int Nd, int qkv, int g)
{
  int total = (Kd/32)*(Nd/16)*64;
  if(g >= total) return;
  int lane = g & 63, fi = g >> 6;
  int ncN = Nd/16;
  int nc = fi % ncN, kc = fi / ncN;
  int Q = lane>>4, L15 = lane&15;
  int n = nc*16 + L15;
  const float* src;
  int stride;
  if(qkv){
    int sec = n>>8, h = (n>>5)&7, kq = n&31;
    const float* Wp = (sec==0)?W0:((sec==1)?W1:W2);
    src = Wp + (size_t)h*256*32 + kq;
    stride = 32;
  } else {
    src = W0 + n;
    stride = Nd;
  }
  #pragma unroll
  for(int j=0;j<8;j++){
    int k = kc*32 + Q*8 + j;
    float v = src[(size_t)k*stride];
    us hb = f2bf_rne(v);
    Bh[(size_t)g*8 + j] = hb;
    Bl[(size_t)g*8 + j] = f2bf_rne(v - us2f(hb));
  }
}

// All 8 weight-prep jobs in one dispatch (block-range routing, 512 blocks).
__global__ void mega_prep(float* __restrict__ ws)
{
  int gb = blockIdx.x;
  int layer = gb >> 8, lb = gb & 255;
  us* prep = (us*)(ws + O_PREP);
  const float* Wq = ws + O_WQ + layer*65536;
  const float* Wk = ws + O_WK + layer*65536;
  const float* Wv = ws + O_WV + layer*65536;
  const float* Wo = ws + O_WO + layer*65536;
  const float* W1 = ws + O_W1 + layer*131072;
  const float* W2 = ws + O_W2 + layer*131072;
  if(lb < 96){
    int g = lb*256 + threadIdx.x;
    prep_b(Wq, Wk, Wv, prep+PQH+(size_t)layer*196608, prep+PQL+(size_t)layer*196608, 256, 768, 1, g);
  } else if(lb < 128){
    int g = (lb-96)*256 + threadIdx.x;
    prep_b(Wo, nullptr, nullptr, prep+POH+(size_t)layer*65536, prep+POL+(size_t)layer*65536, 256, 256, 0, g);
  } else if(lb < 192){
    int g = (lb-128)*256 + threadIdx.x;
    prep_b(W1, nullptr, nullptr, prep+P1H+(size_t)layer*131072, prep+P1L+(size_t)layer*131072, 256, 512, 0, g);
  } else {
    int g = (lb-192)*256 + threadIdx.x;
    prep_b(W2, nullptr, nullptr, prep+P2H+(size_t)layer*131072, prep+P2L+(size_t)layer*131072, 512, 256, 0, g);
  }
}

// Split-bf16 MFMA GEMM. Tile 64x64, 4 waves, 3 MFMAs/frag/K32.
// ASRC 0: A fp32, convert in staging. ASRC 1: A pre-split (global_load_lds).
// ASRC 2: A = merged attention out (sum of 2 key-split partials / sum l).
// B staging always via global_load_lds (lane-linear frag-major).
// MODE 0: QKV -> q fp32; Khi/Klo frag-major; V^T frag-major.
// MODE 1: res+acc. MODE 2: relu(acc+bias). MODE 3: res+acc+bias.
template<int MODE, int ASRC>
__launch_bounds__(256)
__global__ void gemm_mfma(const float* __restrict__ A,
                          const us* __restrict__ Axh, const us* __restrict__ Axl,
                          const float* __restrict__ OpartA, const float* __restrict__ MLA,
                          const us* __restrict__ Bh, const us* __restrict__ Bl,
                          const float* __restrict__ bias, const float* __restrict__ res,
                          float* __restrict__ O,
                          float* __restrict__ qb, us* __restrict__ KH,
                          us* __restrict__ KL, us* __restrict__ VT,
                          int Ncols, int Kdim)
{
  __shared__ __align__(16) us Ah[2048], Al[2048];
  __shared__ __align__(16) us Bhs[2048], Bls[2048];
  const int t = threadIdx.x;
  const int w = t>>6, lane = t&63;
  const int Q = lane>>4, L15 = lane&15;
  const int row0 = blockIdx.x*64;
  const int nc0 = blockIdx.y*4;
  const int col0 = blockIdx.y*64;

  f32x4 acc[2][2];
  #pragma unroll
  for(int i=0;i<2;i++)
    #pragma unroll
    for(int j=0;j<2;j++) acc[i][j] = (f32x4){0.f,0.f,0.f,0.f};

  const int r1 = t>>3;
  const int kl = (t&7)*4;
  const int Qc = kl>>3, j0 = kl&7;
  const int nKc = Kdim>>5;
  const int ncW = Ncols>>4;

  for(int kc=0; kc<nKc; kc++){
    if(ASRC==1){
      size_t abase = ((size_t)(blockIdx.x*nKc + kc))*2048;
      gl_lds16(&Axh[abase + (size_t)t*8], &Ah[t*8]);
      gl_lds16(&Axl[abase + (size_t)t*8], &Al[t*8]);
    } else {
      #pragma unroll
      for(int half=0; half<2; half++){
        int r = r1 + half*32;
        int rg = r>>4, L = r&15;
        float4 v;
        if(ASRC==2){
          int row = row0 + r;
          int b_ = row>>11, s_ = row&2047;
          size_t i0 = (size_t)(b_*8 + kc)*2048 + s_;     // h == kc (Kdim=256)
          float l = MLA[i0] + MLA[i0 + 32768];
          float inv = 1.f/l;
          float4 o0 = *(const float4*)&OpartA[i0*32 + kl];
          float4 o1 = *(const float4*)&OpartA[(i0+32768)*32 + kl];
          v.x=(o0.x+o1.x)*inv; v.y=(o0.y+o1.y)*inv;
          v.z=(o0.z+o1.z)*inv; v.w=(o0.w+o1.w)*inv;
        } else {
          v = *(const float4*)&A[(size_t)(row0+r)*Kdim + kc*32 + kl];
        }
        float f[4] = {v.x, v.y, v.z, v.w};
        us4 h4, l4;
        #pragma unroll
        for(int j=0;j<4;j++){
          us hb = f2bf_rne(f[j]);
          h4[j] = hb; l4[j] = f2bf_rne(f[j] - us2f(hb));
        }
        int off = (rg*4+Qc)*128 + L*8 + j0;
        *(us4*)&Ah[off] = h4;
        *(us4*)&Al[off] = l4;
      }
    }
    {
      size_t gidx = ((size_t)(kc*ncW + nc0 + w)*64 + lane)*8;
      gl_lds16(&Bh[gidx], &Bhs[t*8]);
      gl_lds16(&Bl[gidx], &Bls[t*8]);
    }
    __syncthreads();

    bf16x8 aAh[2], aAl[2], bBh[2], bBl[2];
    #pragma unroll
    for(int rg2=0;rg2<2;rg2++){
      int rg = (w&1)*2 + rg2;
      aAh[rg2] = *(const bf16x8*)&Ah[rg*512 + lane*8];
      aAl[rg2] = *(const bf16x8*)&Al[rg*512 + lane*8];
    }
    #pragma unroll
    for(int cg2=0;cg2<2;cg2++){
      int nc = (w>>1)*2 + cg2;
      bBh[cg2] = *(const bf16x8*)&Bhs[nc*512 + lane*8];
      bBl[cg2] = *(const bf16x8*)&Bls[nc*512 + lane*8];
    }
    #pragma unroll
    for(int rg2=0;rg2<2;rg2++)
      #pragma unroll
      for(int cg2=0;cg2<2;cg2++){
        acc[rg2][cg2] = __builtin_amdgcn_mfma_f32_16x16x32_bf16(aAl[rg2], bBh[cg2], acc[rg2][cg2], 0,0,0);
        acc[rg2][cg2] = __builtin_amdgcn_mfma_f32_16x16x32_bf16(aAh[rg2], bBl[cg2], acc[rg2][cg2], 0,0,0);
        acc[rg2][cg2] = __builtin_amdgcn_mfma_f32_16x16x32_bf16(aAh[rg2], bBh[cg2], acc[rg2][cg2], 0,0,0);
      }
    __syncthreads();
  }

  #pragma unroll
  for(int rg2=0;rg2<2;rg2++)
    #pragma unroll
    for(int cg2=0;cg2<2;cg2++)
      #pragma unroll
      for(int r=0;r<4;r++){
        int row = row0 + (w&1)*32 + rg2*16 + Q*4 + r;
        int c   = col0 + (w>>1)*32 + cg2*16 + L15;
        float va = acc[rg2][cg2][r];
        if(MODE==0){
          int b_ = row>>11, s_ = row&2047;
          int sec = c>>8, h = (c>>5)&7, kq = c&31;
          int bh = b_*NH + h;
          if(sec==0){
            qb[((size_t)bh*SS + s_)*DKk + kq] = va;
          } else if(sec==1){
            us hb = f2bf_rne(va);
            us lb = f2bf_rne(va - us2f(hb));
            size_t idx = ((size_t)(bh*128 + (s_>>4))*64 + (kq>>3)*16 + (s_&15))*8 + (kq&7);
            KH[idx] = hb; KL[idx] = lb;
          } else {
            size_t idx = ((size_t)((bh*64 + (s_>>5))*2 + (kq>>4))*64 + ((s_&31)>>3)*16 + (kq&15))*8 + (s_&7);
            VT[idx] = f2bf_rne(va);
          }
        } else if(MODE==1){
          O[(size_t)row*Ncols + c] = res[(size_t)row*Ncols + c] + va;
        } else if(MODE==2){
          float v = va + bias[c];
          O[(size_t)row*Ncols + c] = v>0.f ? v : 0.f;
        } else {
          O[(size_t)row*Ncols + c] = res[(size_t)row*Ncols + c] + va + bias[c];
        }
      }
}

// MFMA flash attention v6: fixed-shift softmax + key-split x2 + async LDS staging.
// Grid 1024: bh = bx>>6, qt = (bx&63)>>1, ks = bx&1.
// Block = 4 waves = 64 q-rows of one bh over keys [ks*1024, +1024).
__launch_bounds__(256)
__global__ void attn_kernel(const float* __restrict__ qb,
                            const us* __restrict__ KH, const us* __restrict__ KL,
                            const us* __restrict__ VT,
                            const float* __restrict__ mask,
                            float* __restrict__ Opart, float* __restrict__ ML)
{
  __shared__ __align__(16) us Khs[4096], Kls[4096], Vts[4096];
  __shared__ __align__(16) float Msl[128];
  const int t = threadIdx.x;
  const int bh = blockIdx.x >> 6;
  const int qt = (blockIdx.x & 63) >> 1;
  const int ks = blockIdx.x & 1;
  const int b_ = bh >> 3;
  const int wv = t >> 6;
  const int lane = t & 63;
  const int Q = lane >> 4, L15 = lane & 15;
  const int q0 = qt*64 + wv*16;

  bf16x8 qh_v, ql_v;
  {
    const float* qp = &qb[((size_t)bh*SS + q0 + L15)*DKk + Q*8];
    union { us u[8]; bf16x8 v; } uh, ul;
    #pragma unroll
    for(int j=0;j<8;j++){
      float f = qp[j];
      us hb = f2bf_rne(f);
      uh.u[j] = hb; ul.u[j] = f2bf_rne(f - us2f(hb));
    }
    qh_v = uh.v; ql_v = ul.v;
  }

  const us* KHbh = KH + (size_t)bh*65536;
  const us* KLbh = KL + (size_t)bh*65536;
  const us* VTbh = VT + (size_t)bh*65536;

  f32x4 Oa0a = {0.f,0.f,0.f,0.f}, Oa0b = {0.f,0.f,0.f,0.f};
  f32x4 Oa1a = {0.f,0.f,0.f,0.f}, Oa1b = {0.f,0.f,0.f,0.f};
  float lacc = 0.f;

  const int kend = ks*1024 + 1024;
  for(int t0 = ks*1024; t0 < kend; t0 += 128){
    {
      size_t kbase = (size_t)(t0>>4)*512;
      size_t vbase = (size_t)(t0>>5)*1024;
      #pragma unroll
      for(int ii=0; ii<2; ii++){
        int s = t + ii*256;
        gl_lds16(&KHbh[kbase + (size_t)s*8], &Khs[s*8]);
        gl_lds16(&KLbh[kbase + (size_t)s*8], &Kls[s*8]);
        gl_lds16(&VTbh[vbase + (size_t)s*8], &Vts[s*8]);
      }
      if(t < 128) Msl[t] = mask[b_*SS + t0 + t];
    }
    __syncthreads();

    // QK^T -> S^T (3 MFMAs per 16-key tile, 8 tiles)
    f32x4 St[8];
    const f32x4 zz = {0.f,0.f,0.f,0.f};
    #pragma unroll
    for(int kt=0;kt<8;kt++){
      bf16x8 aKh = *(const bf16x8*)&Khs[kt*512 + lane*8];
      bf16x8 aKl = *(const bf16x8*)&Kls[kt*512 + lane*8];
      f32x4 a = __builtin_amdgcn_mfma_f32_16x16x32_bf16(aKl, qh_v, zz, 0,0,0);
      a = __builtin_amdgcn_mfma_f32_16x16x32_bf16(aKh, ql_v, a, 0,0,0);
      a = __builtin_amdgcn_mfma_f32_16x16x32_bf16(aKh, qh_v, a, 0,0,0);
      St[kt] = a;
    }

    // fixed-shift softmax: p = exp(mv*S - 50); no max, no rescale
    float lsum = 0.f;
    #pragma unroll
    for(int kt=0;kt<8;kt++){
      float4 mv = *(const float4*)&Msl[kt*16 + Q*4];
      float mvr[4] = {mv.x, mv.y, mv.z, mv.w};
      #pragma unroll
      for(int r=0;r<4;r++){
        float p = __expf(fmaf(mvr[r], St[kt][r], -SOFT_SHIFT));
        St[kt][r] = p;
        lsum += p;
      }
    }
    lacc += lsum;

    // pack P -> bf16 pairs
    int pk[8][2];
    #pragma unroll
    for(int kt=0;kt<8;kt++){
      int b0 = __float_as_int(St[kt][0]) + 0x8000;
      int b1 = __float_as_int(St[kt][1]) + 0x8000;
      int b2 = __float_as_int(St[kt][2]) + 0x8000;
      int b3 = __float_as_int(St[kt][3]) + 0x8000;
      pk[kt][0] = (b1 & 0xFFFF0000) | ((unsigned)b0 >> 16);
      pk[kt][1] = (b3 & 0xFFFF0000) | ((unsigned)b2 >> 16);
    }

    // PV: O^T += V^T · P^T (chunks 0,1 -> a; 2,3 -> b)
    #pragma unroll
    for(int c=0;c<4;c++){
      union { int i[4]; bf16x8 v; } bu;
      #pragma unroll
      for(int d=0;d<4;d++){
        int srcl = (((Q&1)*2 + (d>>1))<<4) | L15;
        int vlo = __shfl(pk[2*c  ][d&1], srcl, 64);
        int vhi = __shfl(pk[2*c+1][d&1], srcl, 64);
        bu.i[d] = (Q & 2) ? vhi : vlo;
      }
      bf16x8 aV0 = *(const bf16x8*)&Vts[(c*2+0)*512 + lane*8];
      bf16x8 aV1 = *(const bf16x8*)&Vts[(c*2+1)*512 + lane*8];
      if(c < 2){
        Oa0a = __builtin_amdgcn_mfma_f32_16x16x32_bf16(aV0, bu.v, Oa0a, 0,0,0);
        Oa1a = __builtin_amdgcn_mfma_f32_16x16x32_bf16(aV1, bu.v, Oa1a, 0,0,0);
      } else {
        Oa0b = __builtin_amdgcn_mfma_f32_16x16x32_bf16(aV0, bu.v, Oa0b, 0,0,0);
        Oa1b = __builtin_amdgcn_mfma_f32_16x16x32_bf16(aV1, bu.v, Oa1b, 0,0,0);
      }
    }
    __syncthreads();
  }

  f32x4 Oa0 = Oa0a + Oa0b;
  f32x4 Oa1 = Oa1a + Oa1b;
  lacc += __shfl_xor(lacc, 16);
  lacc += __shfl_xor(lacc, 32);

  float* opp = &Opart[((size_t)(ks*16+bh)*SS + q0 + L15)*32];
  #pragma unroll
  for(int r=0;r<4;r++){
    opp[Q*4+r]    = Oa0[r];
    opp[16+Q*4+r] = Oa1[r];
  }
  if(Q==0){
    ML[(size_t)(ks*16+bh)*SS + q0 + L15] = lacc;
  }
}

// LayerNorm over D=256, one row per block, in-place; shfl-based reduction.
// Also emits pre-split xhl and (optionally) the final output.
__launch_bounds__(256)
__global__ void ln_kernel(float* __restrict__ xf, const float* __restrict__ gamma,
                          const float* __restrict__ beta, int gi,
                          us* __restrict__ xh, us* __restrict__ xl,
                          void* __restrict__ out, int write_out,
                          const int* __restrict__ flagp)
{
  __shared__ float s1[4], s2[4];
  const int r = blockIdx.x;
  const int t = threadIdx.x;
  float v = xf[(size_t)r*DD + t];
  float sum = v, sumsq = v*v;
  #pragma unroll
  for(int off=1; off<64; off<<=1){
    sum   += __shfl_xor(sum, off);
    sumsq += __shfl_xor(sumsq, off);
  }
  if((t&63)==0){ s1[t>>6]=sum; s2[t>>6]=sumsq; }
  __syncthreads();
  float tot  = s1[0]+s1[1]+s1[2]+s1[3];
  float tot2 = s2[0]+s2[1]+s2[2]+s2[3];
  float mean = tot*(1.f/DD);
  float var  = tot2*(1.f/DD) - mean*mean;
  float g = gamma[gi], bb = beta[gi];
  float val = (v-mean)*rsqrtf(var+LN_EPS)*g + bb;
  xf[(size_t)r*DD + t] = val;
  us hb = f2bf_rne(val);
  us lb = f2bf_rne(val - us2f(hb));
  size_t xi = xhl_idx(r, t);
  xh[xi] = hb; xl[xi] = lb;
  if(write_out){
    if(*flagp) ((float*)out)[(size_t)r*DD + t] = val;
    else       ((bf16*)out)[(size_t)r*DD + t] = __float2bfloat16(val);
  }
}

extern "C" void kernel_launch(void* const* d_in, const int* in_sizes, int n_in,
                              void* d_out, int out_size, void* d_ws, size_t ws_size,
                              hipStream_t stream)
{
  float* ws = (float*)d_ws;
  int* flagp = (int*)d_ws;

  float* xf  = ws + O_XF;
  float* qb  = ws + O_QB;
  us* KH = (us*)(ws + O_KH);
  us* KL = (us*)(ws + O_KL);
  us* VT = (us*)(ws + O_VT);
  us* XH = (us*)(ws + O_XH);
  us* XL = (us*)(ws + O_XL);
  float* Opart = ws + O_OP;
  float* ML  = ws + O_ML;
  float* fh  = Opart;                   // FFN hidden aliases Opart (dead after Wo-GEMM)
  float* maskf = ws + O_MASK;
  float* b1f = ws + O_B1;
  float* b2f_ = ws + O_B2;
  float* gmf = ws + O_GM;
  float* btf = ws + O_BT;
  us* prep = (us*)(ws + O_PREP);

  detect_kernel<<<1,256,0,stream>>>((const us*)d_in[0], in_sizes[0], flagp);
  mega_conv<<<CONV_BLOCKS,256,0,stream>>>(d_in[0], d_in[1], d_in[2], d_in[3], d_in[4], d_in[5],
                                          d_in[6], d_in[7], d_in[8], d_in[9], d_in[10], d_in[11],
                                          ws, flagp);
  mega_prep<<<512,256,0,stream>>>(ws);

  for(int i=0;i<NL;i++){
    const float* b1i = b1f + (size_t)i*DFF;
    const float* b2i = b2f_ + (size_t)i*DD;

    dim3 g0(64, 12);
    gemm_mfma<0,1><<<g0,256,0,stream>>>(nullptr, XH, XL, nullptr, nullptr,
                                        prep+PQH+(size_t)i*196608, prep+PQL+(size_t)i*196608,
                                        nullptr, nullptr, nullptr, qb, KH, KL, VT, 768, 256);
    attn_kernel<<<1024,256,0,stream>>>(qb, KH, KL, VT, maskf, Opart, ML);
    dim3 g1(64, 4);
    gemm_mfma<1,2><<<g1,256,0,stream>>>(nullptr, nullptr, nullptr, Opart, ML,
                                        prep+POH+(size_t)i*65536, prep+POL+(size_t)i*65536,
                                        nullptr, xf, xf, nullptr, nullptr, nullptr, nullptr, 256, 256);
    ln_kernel<<<MROWS,256,0,stream>>>(xf, gmf, btf, 2*i, XH, XL, d_out, 0, flagp);
    dim3 g2(64, 8);
    gemm_mfma<2,1><<<g2,256,0,stream>>>(nullptr, XH, XL, nullptr, nullptr,
                                        prep+P1H+(size_t)i*131072, prep+P1L+(size_t)i*131072,
                                        b1i, nullptr, fh, nullptr, nullptr, nullptr, nullptr, 512, 256);
    dim3 g3(64, 4);
    gemm_mfma<3,0><<<g3,256,0,stream>>>(fh, nullptr, nullptr, nullptr, nullptr,
                                        prep+P2H+(size_t)i*131072, prep+P2L+(size_t)i*131072,
                                        b2i, xf, xf, nullptr, nullptr, nullptr, nullptr, 256, 512);
    ln_kernel<<<MROWS,256,0,stream>>>(xf, gmf, btf, 2*i+1, XH, XL, d_out, (i==NL-1)?1:0, flagp);
  }
}

// Round 12
// 281.342 us; speedup vs baseline: 1.0820x; 1.0098x over previous
//
#include <hip/hip_runtime.h>
#include <hip/hip_bf16.h>

#define NL 2
#define NH 8
#define DKk 32
#define DVv 32
#define DFF 512
#define DD 256
#define BB 2
#define SS 2048
#define MROWS (BB*SS)            // 4096
#define MASK_VALUE (-1e-30f)
#define LN_EPS 1e-14f
#define L2E 1.4426950408889634f
#define SOFT_SHIFT_L2E (50.0f*L2E)   // fixed softmax shift, in log2 units

typedef __hip_bfloat16 bf16;
typedef unsigned short us;
typedef short bf16x8 __attribute__((ext_vector_type(8)));   // 8 bf16 = 4 VGPRs
typedef float f32x4  __attribute__((ext_vector_type(4)));
typedef unsigned short us4 __attribute__((ext_vector_type(4)));

// ---- workspace layout (floats) ----
#define O_XF   256
#define O_QB   (O_XF+1048576)      // QH (1048576 us) + QL (1048576 us) frag-major
#define O_KH   (O_QB+1048576)
#define O_KL   (O_KH+524288)
#define O_VT   (O_KL+524288)
#define O_XH   (O_VT+524288)       // x pre-split hi (1048576 us)
#define O_XL   (O_XH+524288)       // x pre-split lo
#define O_OP   (O_XL+524288)       // 2097152: key-split x2 partial O (fh aliases)
#define O_ML   (O_OP+2097152)      // 65536: key-split l (m is constant)
#define O_MASK (O_ML+65536)
#define O_WQ   (O_MASK+4096)
#define O_WK   (O_WQ+131072)
#define O_WV   (O_WK+131072)
#define O_WO   (O_WV+131072)
#define O_W1   (O_WO+131072)
#define O_B1   (O_W1+262144)
#define O_W2   (O_B1+1024)
#define O_B2   (O_W2+262144)
#define O_GM   (O_B2+512)
#define O_BT   (O_GM+4)
#define O_PREP (O_BT+4)
// total elements mega_conv must cover (x..beta):
#define CONV_TOTAL (1048576+4096+131072+131072+131072+131072+262144+1024+262144+512+4+4)
#define CONV_BLOCKS ((CONV_TOTAL+255)/256)
// prep region offsets in ushorts (relative to (us*)(ws+O_PREP))
#define PQH 0u
#define PQL 393216u
#define POH 786432u
#define POL 917504u
#define P1H 1048576u
#define P1L 1310720u
#define P2H 1572864u
#define P2L 1835008u

__device__ __forceinline__ float us2f(us u){
  unsigned int v = ((unsigned int)u) << 16; float f;
  __builtin_memcpy(&f, &v, 4); return f;
}
__device__ __forceinline__ us f2bf_rne(float f){
  unsigned int b = __float_as_uint(f);
  b += 0x7FFFu + ((b>>16)&1u);
  return (us)(b>>16);
}

// fast exp2 (v_exp_f32); args here are always <= 0 and > -90, no edge cases
#if __has_builtin(__builtin_amdgcn_exp2f)
#define EXP2F(x) __builtin_amdgcn_exp2f(x)
#else
#define EXP2F(x) exp2f(x)
#endif

// pack two fp32 -> packed bf16 pair (lo16 = a, hi16 = b)
#if __has_builtin(__builtin_amdgcn_cvt_pk_bf16_f32)
typedef __bf16 bf16x2_t __attribute__((ext_vector_type(2)));
__device__ __forceinline__ int pack_bf16(float a, float b){
  bf16x2_t r = __builtin_amdgcn_cvt_pk_bf16_f32(a, b);
  int i; __builtin_memcpy(&i, &r, 4); return i;
}
#else
__device__ __forceinline__ int pack_bf16(float a, float b){
  int b0 = __float_as_int(a) + 0x8000;
  int b1 = __float_as_int(b) + 0x8000;
  return (b1 & 0xFFFF0000) | ((int)((unsigned)b0 >> 16));
}
#endif

// Async global->LDS 16B copy (lane-linear layouts only).
__device__ __forceinline__ void gl_lds16(const us* g, us* l){
  __builtin_amdgcn_global_load_lds(
    (const __attribute__((address_space(1))) unsigned int*)g,
    (__attribute__((address_space(3))) unsigned int*)l, 16, 0, 0);
}

// x pre-split frag-major index for element (row, col), K=256 tiling.
__device__ __forceinline__ size_t xhl_idx(int row, int col){
  int rt = row>>6, rg = (row>>4)&3, L15 = row&15;
  int kc = col>>5, Q = (col>>3)&3, j = col&7;
  return ((size_t)(rt*8+kc))*2048 + rg*512 + Q*128 + L15*8 + j;
}

// Detect whether inputs are bf16 (flag=0) or fp32 (flag=1).
__global__ void detect_kernel(const us* __restrict__ x, int n, int* __restrict__ flagp){
  __shared__ int bad;
  if(threadIdx.x==0) bad = 0;
  __syncthreads();
  int lim = n < 4096 ? n : 4096;
  int mybad = 0;
  for(int i=threadIdx.x; i<lim; i+=256){
    float f = us2f(x[i]);
    if(!(fabsf(f) < 1e3f)) mybad = 1;
  }
  if(mybad) atomicOr(&bad, 1);
  __syncthreads();
  if(threadIdx.x==0) *flagp = bad ? 1 : 0;
}

__device__ __forceinline__ float conv1(const void* src, int i, int flag){
  if(flag) return ((const float*)src)[i];
  return us2f(((const us*)src)[i]);
}

// All 12 input conversions in one dispatch; x also emitted pre-split (xhl).
// Mask is premultiplied by log2(e) for the exp2-based softmax.
__global__ void mega_conv(const void* s0, const void* s1, const void* s2, const void* s3,
                          const void* s4, const void* s5, const void* s6, const void* s7,
                          const void* s8, const void* s9, const void* s10, const void* s11,
                          float* __restrict__ ws, const int* __restrict__ flagp)
{
  int g = blockIdx.x*256 + threadIdx.x;
  int flag = *flagp;
  if(g < 1048576){
    float v = conv1(s0, g, flag);
    ws[O_XF+g] = v;
    us hb = f2bf_rne(v);
    us lb = f2bf_rne(v - us2f(hb));
    size_t xi = xhl_idx(g>>8, g&255);
    ((us*)(ws+O_XH))[xi] = hb;
    ((us*)(ws+O_XL))[xi] = lb;
    return;
  }
  g -= 1048576;
  if(g < 4096){ ws[O_MASK+g] = conv1(s1, g, flag)*L2E; return; }
  g -= 4096;
  if(g < 131072){ ws[O_WQ+g] = conv1(s2, g, flag); return; }
  g -= 131072;
  if(g < 131072){ ws[O_WK+g] = conv1(s3, g, flag); return; }
  g -= 131072;
  if(g < 131072){ ws[O_WV+g] = conv1(s4, g, flag); return; }
  g -= 131072;
  if(g < 131072){ ws[O_WO+g] = conv1(s5, g, flag); return; }
  g -= 131072;
  if(g < 262144){ ws[O_W1+g] = conv1(s6, g, flag); return; }
  g -= 262144;
  if(g < 1024){ ws[O_B1+g] = conv1(s7, g, flag); return; }
  g -= 1024;
  if(g < 262144){ ws[O_W2+g] = conv1(s8, g, flag); return; }
  g -= 262144;
  if(g < 512){ ws[O_B2+g] = conv1(s9, g, flag); return; }
  g -= 512;
  if(g < 4){ ws[O_GM+g] = conv1(s10, g, flag); return; }
  g -= 4;
  if(g < 4){ ws[O_BT+g] = conv1(s11, g, flag); return; }
}

// Build fragment-major hi/lo bf16 B-operands from fp32 weights.
__device__ __forceinline__ void prep_b(const float* W0, const float* W1, const float* W2,
                                       us* Bh, us* Bl, int Kd, int Nd, int qkv, int g)
{
  int total = (Kd/32)*(Nd/16)*64;
  if(g >= total) return;
  int lane = g & 63, fi = g >> 6;
  int ncN = Nd/16;
  int nc = fi % ncN, kc = fi / ncN;
  int Q = lane>>4, L15 = lane&15;
  int n = nc*16 + L15;
  const float* src;
  int stride;
  if(qkv){
    int sec = n>>8, h = (n>>5)&7, kq = n&31;
    const float* Wp = (sec==0)?W0:((sec==1)?W1:W2);
    src = Wp + (size_t)h*256*32 + kq;
    stride = 32;
  } else {
    src = W0 + n;
    stride = Nd;
  }
  #pragma unroll
  for(int j=0;j<8;j++){
    int k = kc*32 + Q*8 + j;
    float v = src[(size_t)k*stride];
    us hb = f2bf_rne(v);
    Bh[(size_t)g*8 + j] = hb;
    Bl[(size_t)g*8 + j] = f2bf_rne(v - us2f(hb));
  }
}

// All 8 weight-prep jobs in one dispatch (block-range routing, 512 blocks).
__global__ void mega_prep(float* __restrict__ ws)
{
  int gb = blockIdx.x;
  int layer = gb >> 8, lb = gb & 255;
  us* prep = (us*)(ws + O_PREP);
  const float* Wq = ws + O_WQ + layer*65536;
  const float* Wk = ws + O_WK + layer*65536;
  const float* Wv = ws + O_WV + layer*65536;
  const float* Wo = ws + O_WO + layer*65536;
  const float* W1 = ws + O_W1 + layer*131072;
  const float* W2 = ws + O_W2 + layer*131072;
  if(lb < 96){
    int g = lb*256 + threadIdx.x;
    prep_b(Wq, Wk, Wv, prep+PQH+(size_t)layer*196608, prep+PQL+(size_t)layer*196608, 256, 768, 1, g);
  } else if(lb < 128){
    int g = (lb-96)*256 + threadIdx.x;
    prep_b(Wo, nullptr, nullptr, prep+POH+(size_t)layer*65536, prep+POL+(size_t)layer*65536, 256, 256, 0, g);
  } else if(lb < 192){
    int g = (lb-128)*256 + threadIdx.x;
    prep_b(W1, nullptr, nullptr, prep+P1H+(size_t)layer*131072, prep+P1L+(size_t)layer*131072, 256, 512, 0, g);
  } else {
    int g = (lb-192)*256 + threadIdx.x;
    prep_b(W2, nullptr, nullptr, prep+P2H+(size_t)layer*131072, prep+P2L+(size_t)layer*131072, 512, 256, 0, g);
  }
}

// Split-bf16 MFMA GEMM. Tile 64x64, 4 waves, 3 MFMAs/frag/K32.
// ASRC 0: A fp32, convert in staging. ASRC 1: A pre-split (global_load_lds).
// ASRC 2: A = merged attention out (sum of 2 key-split partials / sum l).
// MODE 0: QKV -> QH/QL, KH/KL, VT all frag-major bf16.
// MODE 1: res+acc. MODE 2: relu(acc+bias). MODE 3: res+acc+bias.
template<int MODE, int ASRC>
__launch_bounds__(256)
__global__ void gemm_mfma(const float* __restrict__ A,
                          const us* __restrict__ Axh, const us* __restrict__ Axl,
                          const float* __restrict__ OpartA, const float* __restrict__ MLA,
                          const us* __restrict__ Bh, const us* __restrict__ Bl,
                          const float* __restrict__ bias, const float* __restrict__ res,
                          float* __restrict__ O,
                          us* __restrict__ QH, us* __restrict__ QL,
                          us* __restrict__ KH, us* __restrict__ KL, us* __restrict__ VT,
                          int Ncols, int Kdim)
{
  __shared__ __align__(16) us Ah[2048], Al[2048];
  __shared__ __align__(16) us Bhs[2048], Bls[2048];
  const int t = threadIdx.x;
  const int w = t>>6, lane = t&63;
  const int Q = lane>>4, L15 = lane&15;
  const int row0 = blockIdx.x*64;
  const int nc0 = blockIdx.y*4;
  const int col0 = blockIdx.y*64;

  f32x4 acc[2][2];
  #pragma unroll
  for(int i=0;i<2;i++)
    #pragma unroll
    for(int j=0;j<2;j++) acc[i][j] = (f32x4){0.f,0.f,0.f,0.f};

  const int r1 = t>>3;
  const int kl = (t&7)*4;
  const int Qc = kl>>3, j0 = kl&7;
  const int nKc = Kdim>>5;
  const int ncW = Ncols>>4;

  for(int kc=0; kc<nKc; kc++){
    if(ASRC==1){
      size_t abase = ((size_t)(blockIdx.x*nKc + kc))*2048;
      gl_lds16(&Axh[abase + (size_t)t*8], &Ah[t*8]);
      gl_lds16(&Axl[abase + (size_t)t*8], &Al[t*8]);
    } else {
      #pragma unroll
      for(int half=0; half<2; half++){
        int r = r1 + half*32;
        int rg = r>>4, L = r&15;
        float4 v;
        if(ASRC==2){
          int row = row0 + r;
          int b_ = row>>11, s_ = row&2047;
          size_t i0 = (size_t)(b_*8 + kc)*2048 + s_;     // h == kc (Kdim=256)
          float l = MLA[i0] + MLA[i0 + 32768];
          float inv = 1.f/l;
          float4 o0 = *(const float4*)&OpartA[i0*32 + kl];
          float4 o1 = *(const float4*)&OpartA[(i0+32768)*32 + kl];
          v.x=(o0.x+o1.x)*inv; v.y=(o0.y+o1.y)*inv;
          v.z=(o0.z+o1.z)*inv; v.w=(o0.w+o1.w)*inv;
        } else {
          v = *(const float4*)&A[(size_t)(row0+r)*Kdim + kc*32 + kl];
        }
        float f[4] = {v.x, v.y, v.z, v.w};
        us4 h4, l4;
        #pragma unroll
        for(int j=0;j<4;j++){
          us hb = f2bf_rne(f[j]);
          h4[j] = hb; l4[j] = f2bf_rne(f[j] - us2f(hb));
        }
        int off = (rg*4+Qc)*128 + L*8 + j0;
        *(us4*)&Ah[off] = h4;
        *(us4*)&Al[off] = l4;
      }
    }
    {
      size_t gidx = ((size_t)(kc*ncW + nc0 + w)*64 + lane)*8;
      gl_lds16(&Bh[gidx], &Bhs[t*8]);
      gl_lds16(&Bl[gidx], &Bls[t*8]);
    }
    __syncthreads();

    bf16x8 aAh[2], aAl[2], bBh[2], bBl[2];
    #pragma unroll
    for(int rg2=0;rg2<2;rg2++){
      int rg = (w&1)*2 + rg2;
      aAh[rg2] = *(const bf16x8*)&Ah[rg*512 + lane*8];
      aAl[rg2] = *(const bf16x8*)&Al[rg*512 + lane*8];
    }
    #pragma unroll
    for(int cg2=0;cg2<2;cg2++){
      int nc = (w>>1)*2 + cg2;
      bBh[cg2] = *(const bf16x8*)&Bhs[nc*512 + lane*8];
      bBl[cg2] = *(const bf16x8*)&Bls[nc*512 + lane*8];
    }
    #pragma unroll
    for(int rg2=0;rg2<2;rg2++)
      #pragma unroll
      for(int cg2=0;cg2<2;cg2++){
        acc[rg2][cg2] = __builtin_amdgcn_mfma_f32_16x16x32_bf16(aAl[rg2], bBh[cg2], acc[rg2][cg2], 0,0,0);
        acc[rg2][cg2] = __builtin_amdgcn_mfma_f32_16x16x32_bf16(aAh[rg2], bBl[cg2], acc[rg2][cg2], 0,0,0);
        acc[rg2][cg2] = __builtin_amdgcn_mfma_f32_16x16x32_bf16(aAh[rg2], bBh[cg2], acc[rg2][cg2], 0,0,0);
      }
    __syncthreads();
  }

  #pragma unroll
  for(int rg2=0;rg2<2;rg2++)
    #pragma unroll
    for(int cg2=0;cg2<2;cg2++)
      #pragma unroll
      for(int r=0;r<4;r++){
        int row = row0 + (w&1)*32 + rg2*16 + Q*4 + r;
        int c   = col0 + (w>>1)*32 + cg2*16 + L15;
        float va = acc[rg2][cg2][r];
        if(MODE==0){
          int b_ = row>>11, s_ = row&2047;
          int sec = c>>8, h = (c>>5)&7, kq = c&31;
          int bh = b_*NH + h;
          size_t idx = ((size_t)(bh*128 + (s_>>4))*64 + (kq>>3)*16 + (s_&15))*8 + (kq&7);
          if(sec==0){
            us hb = f2bf_rne(va);
            QH[idx] = hb; QL[idx] = f2bf_rne(va - us2f(hb));
          } else if(sec==1){
            us hb = f2bf_rne(va);
            KH[idx] = hb; KL[idx] = f2bf_rne(va - us2f(hb));
          } else {
            size_t vidx = ((size_t)((bh*64 + (s_>>5))*2 + (kq>>4))*64 + ((s_&31)>>3)*16 + (kq&15))*8 + (s_&7);
            VT[vidx] = f2bf_rne(va);
          }
        } else if(MODE==1){
          O[(size_t)row*Ncols + c] = res[(size_t)row*Ncols + c] + va;
        } else if(MODE==2){
          float v = va + bias[c];
          O[(size_t)row*Ncols + c] = v>0.f ? v : 0.f;
        } else {
          O[(size_t)row*Ncols + c] = res[(size_t)row*Ncols + c] + va + bias[c];
        }
      }
}

// MFMA flash attention v7: exp2 softmax (premult mask), cvt_pk pack,
// frag-major Q prologue, key-split x2, async LDS staging.
// Grid 1024: bh = bx>>6, qt = (bx&63)>>1, ks = bx&1.
__launch_bounds__(256)
__global__ void attn_kernel(const us* __restrict__ QH, const us* __restrict__ QL,
                            const us* __restrict__ KH, const us* __restrict__ KL,
                            const us* __restrict__ VT,
                            const float* __restrict__ mask,
                            float* __restrict__ Opart, float* __restrict__ ML)
{
  __shared__ __align__(16) us Khs[4096], Kls[4096], Vts[4096];
  __shared__ __align__(16) float Msl[128];
  const int t = threadIdx.x;
  const int bh = blockIdx.x >> 6;
  const int qt = (blockIdx.x & 63) >> 1;
  const int ks = blockIdx.x & 1;
  const int b_ = bh >> 3;
  const int wv = t >> 6;
  const int lane = t & 63;
  const int Q = lane >> 4, L15 = lane & 15;
  const int q0 = qt*64 + wv*16;

  size_t qidx = ((size_t)(bh*128 + qt*4 + wv)*64 + lane)*8;
  const bf16x8 qh_v = *(const bf16x8*)&QH[qidx];
  const bf16x8 ql_v = *(const bf16x8*)&QL[qidx];

  const us* KHbh = KH + (size_t)bh*65536;
  const us* KLbh = KL + (size_t)bh*65536;
  const us* VTbh = VT + (size_t)bh*65536;

  f32x4 Oa0a = {0.f,0.f,0.f,0.f}, Oa0b = {0.f,0.f,0.f,0.f};
  f32x4 Oa1a = {0.f,0.f,0.f,0.f}, Oa1b = {0.f,0.f,0.f,0.f};
  float lacc = 0.f;

  const int kend = ks*1024 + 1024;
  for(int t0 = ks*1024; t0 < kend; t0 += 128){
    {
      size_t kbase = (size_t)(t0>>4)*512;
      size_t vbase = (size_t)(t0>>5)*1024;
      #pragma unroll
      for(int ii=0; ii<2; ii++){
        int s = t + ii*256;
        gl_lds16(&KHbh[kbase + (size_t)s*8], &Khs[s*8]);
        gl_lds16(&KLbh[kbase + (size_t)s*8], &Kls[s*8]);
        gl_lds16(&VTbh[vbase + (size_t)s*8], &Vts[s*8]);
      }
      if(t < 128) Msl[t] = mask[b_*SS + t0 + t];   // mask pre-scaled by log2e
    }
    __syncthreads();

    // QK^T -> S^T (3 MFMAs per 16-key tile, 8 tiles)
    f32x4 St[8];
    const f32x4 zz = {0.f,0.f,0.f,0.f};
    #pragma unroll
    for(int kt=0;kt<8;kt++){
      bf16x8 aKh = *(const bf16x8*)&Khs[kt*512 + lane*8];
      bf16x8 aKl = *(const bf16x8*)&Kls[kt*512 + lane*8];
      f32x4 a = __builtin_amdgcn_mfma_f32_16x16x32_bf16(aKl, qh_v, zz, 0,0,0);
      a = __builtin_amdgcn_mfma_f32_16x16x32_bf16(aKh, ql_v, a, 0,0,0);
      a = __builtin_amdgcn_mfma_f32_16x16x32_bf16(aKh, qh_v, a, 0,0,0);
      St[kt] = a;
    }

    // fixed-shift softmax in log2 space: p = exp2(mv_l2e * S - 50*l2e)
    float lsum = 0.f;
    #pragma unroll
    for(int kt=0;kt<8;kt++){
      float4 mv = *(const float4*)&Msl[kt*16 + Q*4];
      float mvr[4] = {mv.x, mv.y, mv.z, mv.w};
      #pragma unroll
      for(int r=0;r<4;r++){
        float p = EXP2F(fmaf(mvr[r], St[kt][r], -SOFT_SHIFT_L2E));
        St[kt][r] = p;
        lsum += p;
      }
    }
    lacc += lsum;

    // pack P -> bf16 pairs (v_cvt_pk_bf16_f32 when available)
    int pk[8][2];
    #pragma unroll
    for(int kt=0;kt<8;kt++){
      pk[kt][0] = pack_bf16(St[kt][0], St[kt][1]);
      pk[kt][1] = pack_bf16(St[kt][2], St[kt][3]);
    }

    // PV: O^T += V^T · P^T (chunks 0,1 -> a; 2,3 -> b)
    #pragma unroll
    for(int c=0;c<4;c++){
      union { int i[4]; bf16x8 v; } bu;
      #pragma unroll
      for(int d=0;d<4;d++){
        int srcl = (((Q&1)*2 + (d>>1))<<4) | L15;
        int vlo = __shfl(pk[2*c  ][d&1], srcl, 64);
        int vhi = __shfl(pk[2*c+1][d&1], srcl, 64);
        bu.i[d] = (Q & 2) ? vhi : vlo;
      }
      bf16x8 aV0 = *(const bf16x8*)&Vts[(c*2+0)*512 + lane*8];
      bf16x8 aV1 = *(const bf16x8*)&Vts[(c*2+1)*512 + lane*8];
      if(c < 2){
        Oa0a = __builtin_amdgcn_mfma_f32_16x16x32_bf16(aV0, bu.v, Oa0a, 0,0,0);
        Oa1a = __builtin_amdgcn_mfma_f32_16x16x32_bf16(aV1, bu.v, Oa1a, 0,0,0);
      } else {
        Oa0b = __builtin_amdgcn_mfma_f32_16x16x32_bf16(aV0, bu.v, Oa0b, 0,0,0);
        Oa1b = __builtin_amdgcn_mfma_f32_16x16x32_bf16(aV1, bu.v, Oa1b, 0,0,0);
      }
    }
    __syncthreads();
  }

  f32x4 Oa0 = Oa0a + Oa0b;
  f32x4 Oa1 = Oa1a + Oa1b;
  lacc += __shfl_xor(lacc, 16);
  lacc += __shfl_xor(lacc, 32);

  float* opp = &Opart[((size_t)(ks*16+bh)*SS + q0 + L15)*32];
  #pragma unroll
  for(int r=0;r<4;r++){
    opp[Q*4+r]    = Oa0[r];
    opp[16+Q*4+r] = Oa1[r];
  }
  if(Q==0){
    ML[(size_t)(ks*16+bh)*SS + q0 + L15] = lacc;
  }
}

// LayerNorm over D=256, one row per block, in-place; shfl-based reduction.
// Also emits pre-split xhl and (optionally) the final output.
__launch_bounds__(256)
__global__ void ln_kernel(float* __restrict__ xf, const float* __restrict__ gamma,
                          const float* __restrict__ beta, int gi,
                          us* __restrict__ xh, us* __restrict__ xl,
                          void* __restrict__ out, int write_out,
                          const int* __restrict__ flagp)
{
  __shared__ float s1[4], s2[4];
  const int r = blockIdx.x;
  const int t = threadIdx.x;
  float v = xf[(size_t)r*DD + t];
  float sum = v, sumsq = v*v;
  #pragma unroll
  for(int off=1; off<64; off<<=1){
    sum   += __shfl_xor(sum, off);
    sumsq += __shfl_xor(sumsq, off);
  }
  if((t&63)==0){ s1[t>>6]=sum; s2[t>>6]=sumsq; }
  __syncthreads();
  float tot  = s1[0]+s1[1]+s1[2]+s1[3];
  float tot2 = s2[0]+s2[1]+s2[2]+s2[3];
  float mean = tot*(1.f/DD);
  float var  = tot2*(1.f/DD) - mean*mean;
  float g = gamma[gi], bb = beta[gi];
  float val = (v-mean)*rsqrtf(var+LN_EPS)*g + bb;
  xf[(size_t)r*DD + t] = val;
  us hb = f2bf_rne(val);
  us lb = f2bf_rne(val - us2f(hb));
  size_t xi = xhl_idx(r, t);
  xh[xi] = hb; xl[xi] = lb;
  if(write_out){
    if(*flagp) ((float*)out)[(size_t)r*DD + t] = val;
    else       ((bf16*)out)[(size_t)r*DD + t] = __float2bfloat16(val);
  }
}

extern "C" void kernel_launch(void* const* d_in, const int* in_sizes, int n_in,
                              void* d_out, int out_size, void* d_ws, size_t ws_size,
                              hipStream_t stream)
{
  float* ws = (float*)d_ws;
  int* flagp = (int*)d_ws;

  float* xf  = ws + O_XF;
  us* QHb = (us*)(ws + O_QB);
  us* QLb = QHb + 1048576;
  us* KH = (us*)(ws + O_KH);
  us* KL = (us*)(ws + O_KL);
  us* VT = (us*)(ws + O_VT);
  us* XH = (us*)(ws + O_XH);
  us* XL = (us*)(ws + O_XL);
  float* Opart = ws + O_OP;
  float* ML  = ws + O_ML;
  float* fh  = Opart;                   // FFN hidden aliases Opart (dead after Wo-GEMM)
  float* maskf = ws + O_MASK;
  float* b1f = ws + O_B1;
  float* b2f_ = ws + O_B2;
  float* gmf = ws + O_GM;
  float* btf = ws + O_BT;
  us* prep = (us*)(ws + O_PREP);

  detect_kernel<<<1,256,0,stream>>>((const us*)d_in[0], in_sizes[0], flagp);
  mega_conv<<<CONV_BLOCKS,256,0,stream>>>(d_in[0], d_in[1], d_in[2], d_in[3], d_in[4], d_in[5],
                                          d_in[6], d_in[7], d_in[8], d_in[9], d_in[10], d_in[11],
                                          ws, flagp);
  mega_prep<<<512,256,0,stream>>>(ws);

  for(int i=0;i<NL;i++){
    const float* b1i = b1f + (size_t)i*DFF;
    const float* b2i = b2f_ + (size_t)i*DD;

    dim3 g0(64, 12);
    gemm_mfma<0,1><<<g0,256,0,stream>>>(nullptr, XH, XL, nullptr, nullptr,
                                        prep+PQH+(size_t)i*196608, prep+PQL+(size_t)i*196608,
                                        nullptr, nullptr, nullptr,
                                        QHb, QLb, KH, KL, VT, 768, 256);
    attn_kernel<<<1024,256,0,stream>>>(QHb, QLb, KH, KL, VT, maskf, Opart, ML);
    dim3 g1(64, 4);
    gemm_mfma<1,2><<<g1,256,0,stream>>>(nullptr, nullptr, nullptr, Opart, ML,
                                        prep+POH+(size_t)i*65536, prep+POL+(size_t)i*65536,
                                        nullptr, xf, xf,
                                        nullptr, nullptr, nullptr, nullptr, nullptr, 256, 256);
    ln_kernel<<<MROWS,256,0,stream>>>(xf, gmf, btf, 2*i, XH, XL, d_out, 0, flagp);
    dim3 g2(64, 8);
    gemm_mfma<2,1><<<g2,256,0,stream>>>(nullptr, XH, XL, nullptr, nullptr,
                                        prep+P1H+(size_t)i*131072, prep+P1L+(size_t)i*131072,
                                        b1i, nullptr, fh,
                                        nullptr, nullptr, nullptr, nullptr, nullptr, 512, 256);
    dim3 g3(64, 4);
    gemm_mfma<3,0><<<g3,256,0,stream>>>(fh, nullptr, nullptr, nullptr, nullptr,
                                        prep+P2H+(size_t)i*131072, prep+P2L+(size_t)i*131072,
                                        b2i, xf, xf,
                                        nullptr, nullptr, nullptr, nullptr, nullptr, 256, 512);
    ln_kernel<<<MROWS,256,0,stream>>>(xf, gmf, btf, 2*i+1, XH, XL, d_out, (i==NL-1)?1:0, flagp);
  }
}